// Round 6
// baseline (287.507 us; speedup 1.0000x reference)
//
#include <hip/hip_runtime.h>
#include <hip/hip_bf16.h>
#include <stdint.h>

// Problem constants (reference: B=4, S=2048, D_IN=D_K=D_V=1024)
#define B_ 4
#define S_ 2048
#define D_ 1024

typedef __attribute__((ext_vector_type(8))) short short8;   // 8 bf16 = 4 VGPRs
typedef __attribute__((ext_vector_type(4))) float floatx4;  // MFMA C/D

__device__ __forceinline__ unsigned short bf16_rne(float f) {
  union { float f; uint32_t u; } c; c.f = f;
  uint32_t u = c.u;
  return (unsigned short)((u + 0x7fffu + ((u >> 16) & 1u)) >> 16);
}

__device__ __forceinline__ void gl2lds16(const void* g, void* l) {
  // async global->LDS, 16B per lane; LDS dest is wave-uniform base + lane*16
  __builtin_amdgcn_global_load_lds(
      (const __attribute__((address_space(1))) void*)g,
      (__attribute__((address_space(3))) void*)l, 16, 0, 0);
}

// ---- merged prep: casts of query/key/Wq/Wk, bias packing, value transpose ----
// blocks [0,4608): casts, 4 independent float4 load/store pairs per thread (ILP);
// [4608,4610): bias pack; [4610,6658): 64x64 value transpose tiles with 128B
// coalesced uint2 writes. (Round-5 prep was latency-bound: ILP=1, 64B writes.)
__global__ __launch_bounds__(256) void prep_all(
    const float* __restrict__ q, const float* __restrict__ k,
    const float* __restrict__ wq, const float* __restrict__ wk,
    const float* __restrict__ bq, const float* __restrict__ bk,
    const float* __restrict__ v,
    unsigned short* __restrict__ oq, unsigned short* __restrict__ ok,
    unsigned short* __restrict__ owq, unsigned short* __restrict__ owk,
    float* __restrict__ bias, unsigned short* __restrict__ vt) {
  __shared__ float tile[64][65];  // 65: 2-way banks on both phases (free)
  const int blk = blockIdx.x;
  const int t = threadIdx.x;
  if (blk < 4608) {
    const float* src; unsigned short* dst; int base;  // base in float4 units
    if (blk < 2048)      { src = q;  dst = oq;  base = blk * 1024; }
    else if (blk < 4096) { src = k;  dst = ok;  base = (blk - 2048) * 1024; }
    else if (blk < 4352) { src = wq; dst = owq; base = (blk - 4096) * 1024; }
    else                 { src = wk; dst = owk; base = (blk - 4352) * 1024; }
    float4 v4[4];
#pragma unroll
    for (int p = 0; p < 4; ++p) v4[p] = ((const float4*)src)[base + p * 256 + t];
#pragma unroll
    for (int p = 0; p < 4; ++p) {
      uint32_t p0 = (uint32_t)bf16_rne(v4[p].x) | ((uint32_t)bf16_rne(v4[p].y) << 16);
      uint32_t p1 = (uint32_t)bf16_rne(v4[p].z) | ((uint32_t)bf16_rne(v4[p].w) << 16);
      ((uint2*)dst)[base + p * 256 + t] = make_uint2(p0, p1);
    }
  } else if (blk < 4610) {
    int j = (blk - 4608) * 256 + t;  // 0..511
    const float* src = (j < 256) ? bq : bk;
    ((float4*)bias)[j] = ((const float4*)src)[j & 255];
  } else {
    const int bi = blk - 4610;
    const int d0 = (bi & 15) * 64;          // D/64 = 16
    const int s0 = ((bi >> 4) & 31) * 64;   // S/64 = 32
    const int b  = bi >> 9;                 // B = 4
    const int qi = t & 15, ri = t >> 4;     // 16 lanes x 16 rows
    const float* src = v + (size_t)b * S_ * D_;
#pragma unroll
    for (int p = 0; p < 4; ++p) {
      const int s = p * 16 + ri;
      float4 vv = *(const float4*)(src + (size_t)(s0 + s) * D_ + d0 + qi * 4);
      tile[s][qi * 4 + 0] = vv.x;
      tile[s][qi * 4 + 1] = vv.y;
      tile[s][qi * 4 + 2] = vv.z;
      tile[s][qi * 4 + 3] = vv.w;
    }
    __syncthreads();
    unsigned short* dst = vt + (size_t)b * D_ * S_;
#pragma unroll
    for (int p = 0; p < 4; ++p) {
      const int d = p * 16 + ri;
      uint32_t lo = (uint32_t)bf16_rne(tile[qi * 4 + 0][d]) |
                    ((uint32_t)bf16_rne(tile[qi * 4 + 1][d]) << 16);
      uint32_t hi = (uint32_t)bf16_rne(tile[qi * 4 + 2][d]) |
                    ((uint32_t)bf16_rne(tile[qi * 4 + 3][d]) << 16);
      *(uint2*)(dst + (size_t)(d0 + d) * S_ + s0 + qi * 4) = make_uint2(lo, hi);
    }
  }
}

// ---------------- BT-GEMM: C[m,n] = sum_k A[m,k]*B[n,k], bf16 in, fp32 accum ---------------
// Block tile BM x 128, 4 waves (2x2), wave tile (BM/2) x 64. TWO BK=32 stages
// per barrier pair (round-3 structure -- fastest measured). XOR bank swizzle
// (round-4, zero conflicts): LDS slot (row,c) holds global k-chunk c^((row>>1)&3).
// XCD-aware block remap (round-5: FETCH 133->25MB, 55->45us).
// EPI 0: bf16 = acc + bias[n]; EPI 1: f32 = acc*scale; EPI 2: bf16 = acc*scale.
template <int EPI, int BM>
__global__ __launch_bounds__(256, BM == 128 ? 3 : 2) void gemm_bt(
    const unsigned short* __restrict__ A, const unsigned short* __restrict__ Bm,
    void* __restrict__ Cv, const float* __restrict__ bias,
    int N, int K, float scale,
    long long sA, long long sB, long long sC, long long sBias) {
  constexpr int IC = BM / 32;    // A-frags per wave (m direction)
  constexpr int AST = BM / 64;   // A staging instrs per thread per k32
  __shared__ unsigned short smA[2][BM * 32];
  __shared__ unsigned short smB[2][128 * 32];

  // ---- XCD-aware remap (grid total divisible by 8 for all our launches) ----
  const int gx = gridDim.x, gy = gridDim.y;
  const int lin = blockIdx.x + gx * (blockIdx.y + gy * blockIdx.z);
  const int total = gx * gy * gridDim.z;
  const int g = (lin & 7) * (total >> 3) + (lin >> 3);
  const int z = g / (gx * gy);
  const int rem = g - z * (gx * gy);
  const int by = rem / gx;
  const int bx = rem - by * gx;

  const unsigned short* Ab = A + (size_t)z * sA;
  const unsigned short* Bb = Bm + (size_t)z * sB;

  const int tile_n = bx * 128;
  const int tile_m = by * BM;

  const int t = threadIdx.x;
  const int w = t >> 6;        // wave 0..3
  const int l = t & 63;        // lane
  const int wr = w >> 1, wc = w & 1;  // 2x2 wave grid

  floatx4 acc[IC][4];
#pragma unroll
  for (int i = 0; i < IC; ++i)
#pragma unroll
    for (int j = 0; j < 4; ++j) acc[i][j] = (floatx4){0.f, 0.f, 0.f, 0.f};

  const int srow = l >> 2;                                  // staged quarter-row
  const int scb  = ((l & 3) ^ ((l >> 3) & 3)) * 16;         // swizzled global chunk (bytes)
  const int rm   = l & 15;                                  // fragment row within 16
  const int kcsw = ((l >> 4) ^ ((rm >> 1) & 3)) * 16;       // swizzled LDS chunk (bytes)

  for (int kt = 0; kt < K; kt += 64) {
#pragma unroll
    for (int h = 0; h < 2; ++h) {
#pragma unroll
      for (int i = 0; i < AST; ++i) {
        const int r = (i * 4 + w) * 16 + srow;
        gl2lds16((const char*)Ab + (size_t)(tile_m + r) * K * 2 + (kt + h * 32) * 2 + scb,
                 (char*)smA[h] + (i * 4 + w) * 1024);
      }
#pragma unroll
      for (int i = 0; i < 2; ++i) {
        const int r = (i * 4 + w) * 16 + srow;
        gl2lds16((const char*)Bb + (size_t)(tile_n + r) * K * 2 + (kt + h * 32) * 2 + scb,
                 (char*)smB[h] + (i * 4 + w) * 1024);
      }
    }
    __syncthreads();  // drains vmcnt -> both staged tiles visible

#pragma unroll
    for (int h = 0; h < 2; ++h) {
      short8 bfr[4];
#pragma unroll
      for (int j = 0; j < 4; ++j)
        bfr[j] = *(const short8*)((const char*)smB[h] + (wc * 64 + j * 16 + rm) * 64 + kcsw);
#pragma unroll
      for (int i = 0; i < IC; ++i) {
        const short8 af = *(const short8*)((const char*)smA[h] +
                                           (wr * (BM / 2) + i * 16 + rm) * 64 + kcsw);
#pragma unroll
        for (int j = 0; j < 4; ++j)
          acc[i][j] = __builtin_amdgcn_mfma_f32_16x16x32_bf16(af, bfr[j], acc[i][j], 0, 0, 0);
      }
    }
    __syncthreads();  // protect LDS before next stage
  }

  // Epilogue. C/D layout: col = lane&15, row = (lane>>4)*4 + reg  [m89/m91-verified]
#pragma unroll
  for (int i = 0; i < IC; ++i) {
#pragma unroll
    for (int j = 0; j < 4; ++j) {
      const int n = tile_n + wc * 64 + j * 16 + rm;
      const int m0 = tile_m + wr * (BM / 2) + i * 16 + (l >> 4) * 4;
      if (EPI == 0) {
        const float bv = bias[(size_t)z * sBias + n];
        unsigned short* C = (unsigned short*)Cv + (size_t)z * sC;
#pragma unroll
        for (int r = 0; r < 4; ++r)
          C[(size_t)(m0 + r) * N + n] = bf16_rne(acc[i][j][r] + bv);
      } else if (EPI == 1) {
        float* C = (float*)Cv + (size_t)z * sC;
#pragma unroll
        for (int r = 0; r < 4; ++r)
          C[(size_t)(m0 + r) * N + n] = acc[i][j][r] * scale;
      } else {
        unsigned short* C = (unsigned short*)Cv + (size_t)z * sC;
#pragma unroll
        for (int r = 0; r < 4; ++r)
          C[(size_t)(m0 + r) * N + n] = bf16_rne(acc[i][j][r] * scale);
      }
    }
  }
}

// ------- row softmax: bf16 logits [rows,2048] -> bf16 attn. One WAVE per row -------
// (round-5 softmax was block-per-row with 2 barriers + ILP=1; this is barrier-free
// with 4 independent uint4 loads/lane and shuffle-only reductions.)
__global__ __launch_bounds__(256) void softmax_bf16(
    const unsigned short* __restrict__ logits, unsigned short* __restrict__ attn) {
  const int wv = threadIdx.x >> 6, ln = threadIdx.x & 63;
  const int row = blockIdx.x * 4 + wv;
  const unsigned short* src = logits + (size_t)row * S_;
  uint4 raw[4];
#pragma unroll
  for (int p = 0; p < 4; ++p) raw[p] = *(const uint4*)(src + p * 512 + ln * 8);
  float x[32];
#pragma unroll
  for (int p = 0; p < 4; ++p) {
    const uint32_t ru[4] = {raw[p].x, raw[p].y, raw[p].z, raw[p].w};
#pragma unroll
    for (int i = 0; i < 4; ++i) {
      union { uint32_t u; float f; } lo, hi;
      lo.u = ru[i] << 16;
      hi.u = ru[i] & 0xffff0000u;
      x[p * 8 + 2 * i]     = lo.f;
      x[p * 8 + 2 * i + 1] = hi.f;
    }
  }
  float m = x[0];
#pragma unroll
  for (int i = 1; i < 32; ++i) m = fmaxf(m, x[i]);
#pragma unroll
  for (int off = 32; off > 0; off >>= 1) m = fmaxf(m, __shfl_xor(m, off));
  float s = 0.f;
  const float LOG2E = 1.44269504088896340736f;
#pragma unroll
  for (int i = 0; i < 32; ++i) {
    x[i] = exp2f((x[i] - m) * LOG2E);
    s += x[i];
  }
#pragma unroll
  for (int off = 32; off > 0; off >>= 1) s += __shfl_xor(s, off);
  const float inv = 1.0f / s;
  unsigned short* dst = attn + (size_t)row * S_;
#pragma unroll
  for (int p = 0; p < 4; ++p) {
    uint32_t pk[4];
#pragma unroll
    for (int i = 0; i < 4; ++i)
      pk[i] = (uint32_t)bf16_rne(x[p * 8 + 2 * i] * inv) |
              ((uint32_t)bf16_rne(x[p * 8 + 2 * i + 1] * inv) << 16);
    *(uint4*)(dst + p * 512 + ln * 8) = make_uint4(pk[0], pk[1], pk[2], pk[3]);
  }
}

extern "C" void kernel_launch(void* const* d_in, const int* in_sizes, int n_in,
                              void* d_out, int out_size, void* d_ws, size_t ws_size,
                              hipStream_t stream) {
  (void)in_sizes; (void)n_in; (void)out_size; (void)ws_size;
  const float* query  = (const float*)d_in[0];
  const float* key_in = (const float*)d_in[1];
  const float* value  = (const float*)d_in[2];
  const float* Wq     = (const float*)d_in[3];
  const float* bq     = (const float*)d_in[4];
  const float* Wk     = (const float*)d_in[5];
  const float* bk     = (const float*)d_in[6];
  // d_in[7]=Wv, d_in[8]=bv: unused by the reference math (original model quirk).
  float* out = (float*)d_out;

  // Workspace layout (149 MiB used; every byte written before read each call)
  char* ws = (char*)d_ws;
  const size_t MiB = 1024 * 1024;
  unsigned short* Xq  = (unsigned short*)(ws);              // 16 MiB  query bf16
  unsigned short* Xk  = (unsigned short*)(ws + 16 * MiB);   // 16 MiB  key_in bf16 (contiguous after Xq)
  unsigned short* Wqb = (unsigned short*)(ws + 32 * MiB);   //  2 MiB  Wq bf16
  unsigned short* Wkb = (unsigned short*)(ws + 34 * MiB);   //  2 MiB  Wk bf16 (contiguous after Wqb)
  float*          Bias= (float*)(ws + 36 * MiB);            //  8 KiB  [bq | bk] packed
  unsigned short* Vt  = (unsigned short*)(ws + 37 * MiB);   // 16 MiB  value^T bf16 [B,D,S]
  unsigned short* Qp  = (unsigned short*)(ws + 53 * MiB);   // 16 MiB  Q bf16
  unsigned short* Kp  = (unsigned short*)(ws + 69 * MiB);   // 16 MiB  K bf16 (contiguous after Qp)
  unsigned short* Lg  = (unsigned short*)(ws + 85 * MiB);   // 32 MiB  logits bf16
  unsigned short* At  = (unsigned short*)(ws + 117 * MiB);  // 32 MiB  attn bf16

  // 1) all casts + bias pack + value transpose in one dispatch
  prep_all<<<6658, 256, 0, stream>>>(query, key_in, Wq, Wk, bq, bk, value,
                                     Xq, Xk, Wqb, Wkb, Bias, Vt);

  // 2) Q & K projections fused via z (BM=256: grid 8x32x2 = 512)
  gemm_bt<0, 256><<<dim3(D_ / 128, B_ * S_ / 256, 2), 256, 0, stream>>>(
      Xq, Wqb, Qp, Bias, D_, D_, 0.f,
      (long long)B_ * S_ * D_, (long long)D_ * D_, (long long)B_ * S_ * D_, D_);

  // 3) logits = Q@K^T * D^-0.5 per batch -> bf16 (BM=256: grid 16x8x4 = 512)
  gemm_bt<2, 256><<<dim3(S_ / 128, S_ / 256, B_), 256, 0, stream>>>(
      Qp, Kp, Lg, nullptr, S_, D_, 0.03125f,
      (long long)S_ * D_, (long long)S_ * D_, (long long)S_ * S_, 0);

  // 4) attn = softmax(logits) rowwise -> bf16 (one wave/row, 4 rows/block)
  softmax_bf16<<<B_ * S_ / 4, 256, 0, stream>>>(Lg, At);

  // 5) out = attn @ value == BT-GEMM vs Vt (BM=128: grid 8x16x4 = 512)
  gemm_bt<1, 128><<<dim3(D_ / 128, S_ / 128, B_), 256, 0, stream>>>(
      At, Vt, out, nullptr, D_, S_, 1.0f,
      (long long)S_ * S_, (long long)D_ * S_, (long long)S_ * D_, 0);
}